// Round 4
// baseline (2494.518 us; speedup 1.0000x reference)
//
#include <hip/hip_runtime.h>
#include <hip/hip_bf16.h>
#include <math.h>

// Problem constants
#define BB 128
#define TT 1024
#define DD 256
#define HH 256
#define MM (BB * TT)
#define NN3 768

typedef __attribute__((ext_vector_type(8))) short short8;
typedef __attribute__((ext_vector_type(4))) float f32x4;
typedef __attribute__((address_space(1))) unsigned int gu32;
typedef __attribute__((address_space(3))) unsigned int lu32;

static __device__ __forceinline__ float bf2f(unsigned int u16) {
    return __uint_as_float(u16 << 16);
}
// RNE
static __device__ __forceinline__ unsigned short f2bf(float f) {
    unsigned int u = __float_as_uint(f);
    unsigned int r = u + 0x7FFFu + ((u >> 16) & 1u);
    return (unsigned short)(r >> 16);
}
// round-half-up, 2 ops (per-step activations)
static __device__ __forceinline__ unsigned short f2bf_fast(float f) {
    return (unsigned short)((__float_as_uint(f) + 0x8000u) >> 16);
}

static __device__ __forceinline__ void barrier_lgkm() {
    asm volatile("s_waitcnt lgkmcnt(0)\n\ts_barrier" ::: "memory");
}

// ---------------------------------------------------------------------------
// Kernel A: transpose+convert W -> Wb[768][256] bf16 (row n = gate*256+col,
// entries along k). One block per n-row.
// ---------------------------------------------------------------------------
__global__ __launch_bounds__(256) void wb_kernel(
    const float* __restrict__ Wz, const float* __restrict__ Wr,
    const float* __restrict__ Wh, unsigned short* __restrict__ Wb)
{
    int n = blockIdx.x;          // 0..767
    int g = n >> 8, col = n & 255;
    const float* W = (g == 0) ? Wz : (g == 1 ? Wr : Wh);
    int k = threadIdx.x;         // 0..255
    Wb[(size_t)n * 256 + k] = f2bf(W[(size_t)k * HH + col]);
}

// ---------------------------------------------------------------------------
// Kernel B: xproj via bf16 MFMA, M-major / batch-fragment restructure.
// (unchanged from R3 — its ~370 us is unexplained by roofline arithmetic;
// no blind edits until its counters are understood.)
// ---------------------------------------------------------------------------
__global__ __launch_bounds__(256)
__attribute__((amdgpu_waves_per_eu(4, 4)))
void xproj_mfma(
    const float* __restrict__ x, const unsigned short* __restrict__ Wb,
    const float* __restrict__ bz, const float* __restrict__ br,
    const float* __restrict__ bh, unsigned short* __restrict__ xw)
{
    const int tid  = threadIdx.x;
    const int lane = tid & 63;
    const int wv   = tid >> 6;
    const int nq   = lane & 15;
    const int kq   = lane >> 4;

    const int bid = blockIdx.x >> 7;          // 0..7
    const int t0  = (blockIdx.x & 127) * 8;   // 0..1016
    const int tw0 = t0 + wv * 2;

    // x fragments, register-resident: af[c][mi], 64 VGPRs.
    // A row (nq) = batch-in-16; k = c*32 + kq*8 .. +7.
    short8 af[8][2];
#pragma unroll
    for (int mi = 0; mi < 2; ++mi) {
        const float* xrow = &x[((size_t)(bid * 16 + nq) * 1024 + (tw0 + mi)) * 256];
#pragma unroll
        for (int c = 0; c < 8; ++c) {
            const float* xp = xrow + c * 32 + kq * 8;
            float4 f0 = *(const float4*)xp;
            float4 f1 = *(const float4*)(xp + 4);
            short8 a;
            a[0] = (short)f2bf(f0.x); a[1] = (short)f2bf(f0.y);
            a[2] = (short)f2bf(f0.z); a[3] = (short)f2bf(f0.w);
            a[4] = (short)f2bf(f1.x); a[5] = (short)f2bf(f1.y);
            a[6] = (short)f2bf(f1.z); a[7] = (short)f2bf(f1.w);
            af[c][mi] = a;
        }
    }

#pragma unroll
    for (int g = 0; g < 3; ++g) {
        const float* bias = (g == 0) ? bz : (g == 1 ? br : bh);
#pragma unroll 2
        for (int s = 0; s < 16; ++s) {
            const int st = g * 16 + s;   // == gate-tile index ti in xw layout
            short8 wf[8];
#pragma unroll
            for (int c = 0; c < 8; ++c)
                wf[c] = *(const short8*)&Wb[(size_t)(st * 16 + nq) * 256
                                            + c * 32 + kq * 8];
            const float bv = bias[s * 16 + nq];

            f32x4 acc0 = (f32x4){0.f, 0.f, 0.f, 0.f};
            f32x4 acc1 = (f32x4){0.f, 0.f, 0.f, 0.f};
#pragma unroll
            for (int c = 0; c < 8; ++c) {
                acc0 = __builtin_amdgcn_mfma_f32_16x16x32_bf16(af[c][0], wf[c], acc0, 0, 0, 0);
                acc1 = __builtin_amdgcn_mfma_f32_16x16x32_bf16(af[c][1], wf[c], acc1, 0, 0, 0);
            }

#pragma unroll
            for (int mi = 0; mi < 2; ++mi) {
                f32x4 a = (mi == 0) ? acc0 : acc1;
                unsigned int lo = (unsigned int)f2bf(a[0] + bv)
                                | ((unsigned int)f2bf(a[1] + bv) << 16);
                unsigned int hi = (unsigned int)f2bf(a[2] + bv)
                                | ((unsigned int)f2bf(a[3] + bv) << 16);
                uint2 val; val.x = lo; val.y = hi;
                *(uint2*)&xw[(size_t)((tw0 + mi) * 8 + bid) * 12288
                             + st * 256 + kq * 64 + nq * 4] = val;
            }
        }
    }
}

// ---------------------------------------------------------------------------
// Kernel C: persistent-register MFMA GRU recurrence.
// 8 blocks x 1024 threads (16 waves, 4/SIMD).
// R4: x-staging LDS round-trip ELIMINATED. Each staged byte was read exactly
// once by exactly one lane, so global_load_lds -> LDS -> ds_read was pure
// LDS-pipe waste (write port + 48 b64 reads/step + vmcnt(0) barrier drain).
// Now: 3 coalesced global uint2 loads per lane, register double-buffered one
// step ahead (named buffers -> all compile-time indexing). Barriers are
// lgkm-only. Everything else identical to R3's 2106-us config.
// ---------------------------------------------------------------------------
__global__ __launch_bounds__(1024)
__attribute__((amdgpu_waves_per_eu(4, 4)))
void gru_rec_kernel(
    const unsigned short* __restrict__ xw,
    const float* __restrict__ Uz, const float* __restrict__ Ur,
    const float* __restrict__ Uh,
    float* __restrict__ out)
{
    __shared__ short hA[16][264];    // h bf16, stride 132 dw
    __shared__ short rhA[16][264];   // r*h bf16

    const int tid  = threadIdx.x;
    const int lane = tid & 63;
    const int wv   = tid >> 6;       // 0..15
    const int nq   = lane & 15;
    const int kq   = lane >> 4;
    const int bid  = blockIdx.x;
    const int col0 = wv * 16;        // this wave's 16-column tile

    // ---- persistent weight fragments: 3 gates x 8 k-chunks = 96 regs/lane ----
    short8 wz[8], wr[8], whv[8];
#pragma unroll
    for (int c = 0; c < 8; ++c) {
        short8 fz, fr, fh;
#pragma unroll
        for (int j = 0; j < 8; ++j) {
            size_t rowoff = (size_t)(c * 32 + kq * 8 + j) * HH + col0 + nq;
            fz[j] = (short)f2bf(Uz[rowoff]);
            fr[j] = (short)f2bf(Ur[rowoff]);
            fh[j] = (short)f2bf(Uh[rowoff]);
        }
        wz[c] = fz; wr[c] = fr; whv[c] = fh;
    }

    for (int idx = tid; idx < 16 * 264; idx += 1024) ((short*)hA)[idx] = 0;
    float hprev[4];
#pragma unroll
    for (int i = 0; i < 4; ++i) hprev[i] = 0.f;

    // per-lane xw source: 3 uint2 per step (z, r, h inits), coalesced
    // 512 B per wave. Step stride = 8*12288 shorts.
    const unsigned short* xlane =
        xw + (size_t)bid * 12288 + (size_t)(wv * 64 + lane) * 4;

    uint2 xb0[3], xb1[3];   // named double buffers (compile-time indexed)
    auto ldx = [&](int t, uint2* dst) {
        const unsigned short* p = xlane + (size_t)t * (8 * 12288);
        dst[0] = *(const uint2*)(p);
        dst[1] = *(const uint2*)(p + 4096);
        dst[2] = *(const uint2*)(p + 8192);
    };
    ldx(0, xb0);

    barrier_lgkm();   // hA zero-fill visibility

    auto step = [&](int t, int par) {
        uint2* cur = par ? xb1 : xb0;
        uint2* nxt = par ? xb0 : xb1;
        int tn = (t + 1 < TT) ? (t + 1) : (TT - 1);
        ldx(tn, nxt);   // prefetch next step's x into the other buffer

        // ---- phase A: acc init = x (z,r), then MFMA chains over h ----
        f32x4 accZ, accR;
        {
            uint2 uz = cur[0];
            uint2 ur = cur[1];
            accZ[0] = bf2f(uz.x & 0xffffu);
            accZ[1] = bf2f(uz.x >> 16);
            accZ[2] = bf2f(uz.y & 0xffffu);
            accZ[3] = bf2f(uz.y >> 16);
            accR[0] = bf2f(ur.x & 0xffffu);
            accR[1] = bf2f(ur.x >> 16);
            accR[2] = bf2f(ur.y & 0xffffu);
            accR[3] = bf2f(ur.y >> 16);
        }
#pragma unroll
        for (int c = 0; c < 8; ++c) {
            short8 af = *(const short8*)&hA[nq][c * 32 + kq * 8];
            accZ = __builtin_amdgcn_mfma_f32_16x16x32_bf16(af, wz[c], accZ, 0, 0, 0);
            accR = __builtin_amdgcn_mfma_f32_16x16x32_bf16(af, wr[c], accR, 0, 0, 0);
        }

        // r epilogue only (z deferred to phase B; accZ stays live)
#pragma unroll
        for (int i = 0; i < 4; ++i) {
            float r = __builtin_amdgcn_fmed3f(
                __builtin_fmaf(0.2f, accR[i], 0.5f), 0.f, 1.f);
            rhA[kq * 4 + i][col0 + nq] = (short)f2bf_fast(r * hprev[i]);
        }
        barrier_lgkm();

        // ---- phase B: accH init = xh, MFMA over r*h, z + h epilogue ----
        f32x4 accH;
        {
            uint2 u = cur[2];
            accH[0] = bf2f(u.x & 0xffffu);
            accH[1] = bf2f(u.x >> 16);
            accH[2] = bf2f(u.y & 0xffffu);
            accH[3] = bf2f(u.y >> 16);
        }
#pragma unroll
        for (int c = 0; c < 8; ++c) {
            short8 af = *(const short8*)&rhA[nq][c * 32 + kq * 8];
            accH = __builtin_amdgcn_mfma_f32_16x16x32_bf16(af, whv[c], accH, 0, 0, 0);
        }

#pragma unroll
        for (int i = 0; i < 4; ++i) {
            float z = __builtin_amdgcn_fmed3f(
                __builtin_fmaf(0.2f, accZ[i], 0.5f), 0.f, 1.f);
            float a = __builtin_amdgcn_fmed3f(accH[i], -12.f, 12.f);
            float e  = exp2f(a * 2.88539008f);          // e^(2a)
            float hh = __builtin_fmaf(-2.f, __builtin_amdgcn_rcpf(e + 1.f), 1.f);
            float hn = __builtin_fmaf(z, hprev[i] - hh, hh);
            hprev[i] = hn;
            hA[kq * 4 + i][col0 + nq] = (short)f2bf_fast(hn);
        }
        barrier_lgkm();
    };

    for (int t = 0; t < TT; t += 2) {
        step(t, 0);
        step(t + 1, 1);
    }

#pragma unroll
    for (int i = 0; i < 4; ++i)
        out[(size_t)(bid * 16 + kq * 4 + i) * HH + col0 + nq] = hprev[i];
}

// ---------------------------------------------------------------------------
extern "C" void kernel_launch(void* const* d_in, const int* in_sizes, int n_in,
                              void* d_out, int out_size, void* d_ws, size_t ws_size,
                              hipStream_t stream) {
    const float* x  = (const float*)d_in[0];
    const float* Wz = (const float*)d_in[1];
    const float* Wr = (const float*)d_in[2];
    const float* Wh = (const float*)d_in[3];
    const float* Uz = (const float*)d_in[4];
    const float* Ur = (const float*)d_in[5];
    const float* Uh = (const float*)d_in[6];
    const float* bz = (const float*)d_in[7];
    const float* br = (const float*)d_in[8];
    const float* bh = (const float*)d_in[9];
    float* out = (float*)d_out;

    // workspace: [xw: 192 MiB bf16][Wb: 768*256 bf16 = 384 KiB]
    unsigned short* xw = (unsigned short*)d_ws;
    unsigned short* Wb =
        (unsigned short*)((char*)d_ws + (size_t)MM * NN3 * sizeof(unsigned short));

    wb_kernel<<<NN3, 256, 0, stream>>>(Wz, Wr, Wh, Wb);

    // 1024 blocks: 8 bid-groups x 128 t-chunks of 8 timesteps
    xproj_mfma<<<1024, 256, 0, stream>>>(x, Wb, bz, br, bh, xw);

    gru_rec_kernel<<<8, 1024, 0, stream>>>(xw, Uz, Ur, Uh, out);
}